// Round 1
// baseline (213.128 us; speedup 1.0000x reference)
//
#include <hip/hip_runtime.h>
#include <hip/hip_bf16.h>

#define N_NODES  50000
#define N_EDGES  600000
#define D_IN     128
#define H        64
#define N_GRAPHS 500
#define MAXDEG   64   // in-degree ~ Poisson(12); P(>64) ~ 1e-30
#define SPLIT    4    // blocks per graph in gather

// ---------------------------------------------------------------------------
// Pass 1: bucket-scatter edges by dst. deg[] doubles as the bucket cursor and
// (afterwards) the in-degree count used for the mean.
__global__ void scatter_kernel(const int* __restrict__ src, const int* __restrict__ dst,
                               int* __restrict__ deg, int* __restrict__ col) {
    int e = blockIdx.x * blockDim.x + threadIdx.x;
    if (e >= N_EDGES) return;
    int d = dst[e];
    int pos = atomicAdd(&deg[d], 1);
    if (pos < MAXDEG) col[(size_t)d * MAXDEG + pos] = src[e];
}

// ---------------------------------------------------------------------------
// Pass 2: graph segment boundaries via binary search over sorted batch[].
// gstart[g] = first node index with batch >= g; gstart[N_GRAPHS] = N_NODES.
__global__ void gstart_kernel(const int* __restrict__ batch, int* __restrict__ gstart) {
    int g = blockIdx.x * blockDim.x + threadIdx.x;
    if (g > N_GRAPHS) return;
    int lo = 0, hi = N_NODES;
    while (lo < hi) {
        int mid = (lo + hi) >> 1;
        if (batch[mid] < g) lo = mid + 1; else hi = mid;
    }
    gstart[g] = lo;
}

// ---------------------------------------------------------------------------
// Pass 3 (hot): per-graph pooled accumulators.
//   Pn[g][f] += (1/deg(n)) * sum_{src->n} x[src][f]   for nodes n in graph g
//   Px[g][f] += x[n][f]
// One wave per node; lane l owns features {2l, 2l+1} (float2 -> 512B coalesced
// row loads). SPLIT blocks per graph, register accumulation, then a handful of
// global atomics (256 floats * 2 arrays per block).
__global__ __launch_bounds__(256) void gather_kernel(
        const float* __restrict__ x, const int* __restrict__ col,
        const int* __restrict__ deg, const int* __restrict__ gstart,
        float* __restrict__ Pn, float* __restrict__ Px) {
    int g    = blockIdx.x / SPLIT;
    int s    = blockIdx.x % SPLIT;
    int wave = threadIdx.x >> 6;
    int lane = threadIdx.x & 63;
    int n0 = gstart[g], n1 = gstart[g + 1];

    float2 pn = make_float2(0.f, 0.f);
    float2 px = make_float2(0.f, 0.f);

    for (int n = n0 + s * 4 + wave; n < n1; n += 4 * SPLIT) {
        const float2* xr = (const float2*)(x + (size_t)n * D_IN) + lane;
        float2 v = *xr;
        px.x += v.x; px.y += v.y;

        int d = deg[n];  // wave-uniform
        const int* cl = col + (size_t)n * MAXDEG;
        float2 tmp = make_float2(0.f, 0.f);
        for (int j = 0; j < d; ++j) {
            int sn = cl[j];  // wave-uniform broadcast
            const float2* xs = (const float2*)(x + (size_t)sn * D_IN) + lane;
            float2 u = *xs;
            tmp.x += u.x; tmp.y += u.y;
        }
        if (d > 0) {
            float w = 1.f / (float)d;
            pn.x = fmaf(tmp.x, w, pn.x);
            pn.y = fmaf(tmp.y, w, pn.y);
        }
    }
    atomicAdd(&Pn[g * D_IN + 2 * lane],     pn.x);
    atomicAdd(&Pn[g * D_IN + 2 * lane + 1], pn.y);
    atomicAdd(&Px[g * D_IN + 2 * lane],     px.x);
    atomicAdd(&Px[g * D_IN + 2 * lane + 1], px.y);
}

// ---------------------------------------------------------------------------
// Pass 4: per-graph  h = (Pn@Wl + Px@Wr)/gcnt + bl  followed by the MLP.
// 500 blocks x 64 threads; entirely L2-resident weights.
__global__ void final_kernel(
        const float* __restrict__ Pn, const float* __restrict__ Px,
        const float* __restrict__ Wl, const float* __restrict__ bl,
        const float* __restrict__ Wr,
        const float* __restrict__ W0, const float* __restrict__ b0,
        const float* __restrict__ W1, const float* __restrict__ b1,
        const float* __restrict__ W2, const float* __restrict__ b2,
        const float* __restrict__ W3, const float* __restrict__ b3,
        const int* __restrict__ gstart, float* __restrict__ out) {
    int g = blockIdx.x;
    int t = threadIdx.x;  // 64 threads
    __shared__ float h[H];
    __shared__ float a0[32];
    __shared__ float a1[16];
    __shared__ float a2[8];

    int ng = gstart[g + 1] - gstart[g];
    const float* pn = Pn + (size_t)g * D_IN;
    const float* px = Px + (size_t)g * D_IN;
    float acc = 0.f;
    for (int d = 0; d < D_IN; ++d)
        acc += pn[d] * Wl[d * H + t] + px[d] * Wr[d * H + t];
    // empty graph: gsum==0 -> h==0 in the reference (bias is summed per node)
    h[t] = (ng > 0) ? (acc / (float)ng + bl[t]) : 0.f;
    __syncthreads();

    if (t < 32) { float a = b0[t]; for (int d = 0; d < H;  ++d) a += h[d]  * W0[d * 32 + t]; a0[t] = fmaxf(a, 0.f); }
    __syncthreads();
    if (t < 16) { float a = b1[t]; for (int d = 0; d < 32; ++d) a += a0[d] * W1[d * 16 + t]; a1[t] = fmaxf(a, 0.f); }
    __syncthreads();
    if (t < 8)  { float a = b2[t]; for (int d = 0; d < 16; ++d) a += a1[d] * W2[d * 8 + t];  a2[t] = fmaxf(a, 0.f); }
    __syncthreads();
    if (t == 0) { float a = b3[0]; for (int d = 0; d < 8;  ++d) a += a2[d] * W3[d]; out[g] = a; }
}

// ---------------------------------------------------------------------------
extern "C" void kernel_launch(void* const* d_in, const int* in_sizes, int n_in,
                              void* d_out, int out_size, void* d_ws, size_t ws_size,
                              hipStream_t stream) {
    const float* x     = (const float*)d_in[0];
    const int*   ei    = (const int*)  d_in[1];   // [2, N_EDGES]: row0=src, row1=dst
    const int*   batch = (const int*)  d_in[2];
    const float* Wl    = (const float*)d_in[3];
    const float* bl    = (const float*)d_in[4];
    const float* Wr    = (const float*)d_in[5];
    const float* W0    = (const float*)d_in[6];
    const float* b0    = (const float*)d_in[7];
    const float* W1    = (const float*)d_in[8];
    const float* b1    = (const float*)d_in[9];
    const float* W2    = (const float*)d_in[10];
    const float* b2    = (const float*)d_in[11];
    const float* W3    = (const float*)d_in[12];
    const float* b3    = (const float*)d_in[13];
    float* out = (float*)d_out;

    // workspace layout (256B aligned)
    char* ws = (char*)d_ws;
    int*   deg    = (int*)(ws + 0);                       // 50000 ints   (200000 B)
    int*   col    = (int*)(ws + 200704);                  // 50000*64 ints (12.8 MB)
    int*   gstart = (int*)(ws + 200704 + 12800000);       // 501 ints
    float* Pn     = (float*)(ws + 200704 + 12800000 + 4096); // 500*128 f
    float* Px     = Pn + N_GRAPHS * D_IN;                    // 500*128 f

    hipMemsetAsync(deg, 0, N_NODES * sizeof(int), stream);
    hipMemsetAsync(Pn, 0, 2 * N_GRAPHS * D_IN * sizeof(float), stream);

    scatter_kernel<<<(N_EDGES + 255) / 256, 256, 0, stream>>>(ei, ei + N_EDGES, deg, col);
    gstart_kernel<<<2, 256, 0, stream>>>(batch, gstart);
    gather_kernel<<<N_GRAPHS * SPLIT, 256, 0, stream>>>(x, col, deg, gstart, Pn, Px);
    final_kernel<<<N_GRAPHS, 64, 0, stream>>>(Pn, Px, Wl, bl, Wr,
                                              W0, b0, W1, b1, W2, b2, W3, b3,
                                              gstart, out);
}

// Round 2
// 189.571 us; speedup vs baseline: 1.1243x; 1.1243x over previous
//
#include <hip/hip_runtime.h>
#include <hip/hip_bf16.h>

#define N_NODES  50000
#define N_EDGES  600000
#define D_IN     128
#define H        64
#define N_GRAPHS 500
#define MAXDEG   48   // in-degree ~ Poisson(12); max over 50K nodes ~33. P(>48) < 1e-28
#define SPLIT    8    // blocks per graph in gather

#define CONV_BLOCKS 6250   // 6.4M floats / 4-per-thread / 256 threads
#define SCAT_BLOCKS 2344   // ceil(600000/256)
#define GST_BLOCKS  2      // 501 threads

__device__ __forceinline__ float bf2f(unsigned short h) {
    return __uint_as_float(((unsigned int)h) << 16);
}

// ---------------------------------------------------------------------------
// Fused prep: (a) x fp32 -> bf16, (b) bucket-scatter edges by dst,
// (c) graph segment starts via binary search. All independent.
__global__ __launch_bounds__(256) void prep_kernel(
        const float* __restrict__ x, unsigned short* __restrict__ xb,
        const int* __restrict__ src, const int* __restrict__ dst,
        int* __restrict__ deg, int* __restrict__ col,
        const int* __restrict__ batch, int* __restrict__ gstart) {
    int bid = blockIdx.x;
    if (bid < CONV_BLOCKS) {
        int i = bid * 256 + threadIdx.x;          // group of 4 floats
        float4 f = ((const float4*)x)[i];
        ushort4 u;
        u.x = __bfloat16_as_ushort(__float2bfloat16(f.x));
        u.y = __bfloat16_as_ushort(__float2bfloat16(f.y));
        u.z = __bfloat16_as_ushort(__float2bfloat16(f.z));
        u.w = __bfloat16_as_ushort(__float2bfloat16(f.w));
        ((ushort4*)xb)[i] = u;
    } else if (bid < CONV_BLOCKS + SCAT_BLOCKS) {
        int e = (bid - CONV_BLOCKS) * 256 + threadIdx.x;
        if (e < N_EDGES) {
            int d = dst[e];
            int pos = atomicAdd(&deg[d], 1);
            if (pos < MAXDEG) col[(size_t)d * MAXDEG + pos] = src[e];
        }
    } else {
        int g = (bid - CONV_BLOCKS - SCAT_BLOCKS) * 256 + threadIdx.x;
        if (g <= N_GRAPHS) {
            int lo = 0, hi = N_NODES;
            while (lo < hi) {
                int mid = (lo + hi) >> 1;
                if (batch[mid] < g) lo = mid + 1; else hi = mid;
            }
            gstart[g] = lo;
        }
    }
}

// ---------------------------------------------------------------------------
// Hot pass: per-graph pooled accumulators from bf16 rows (256 B/row).
// Lane l owns features {2l, 2l+1}. Neighbor indices fetched with ONE coalesced
// lane-parallel load + __shfl broadcast, 4-way unrolled row loads for MLP.
__global__ __launch_bounds__(256) void gather_kernel(
        const unsigned short* __restrict__ xb, const int* __restrict__ col,
        const int* __restrict__ deg, const int* __restrict__ gstart,
        float* __restrict__ Pn, float* __restrict__ Px) {
    __shared__ float sacc[2 * D_IN];
    if (threadIdx.x < 2 * D_IN) sacc[threadIdx.x] = 0.f;
    __syncthreads();

    int g    = blockIdx.x / SPLIT;
    int s    = blockIdx.x % SPLIT;
    int wave = threadIdx.x >> 6;
    int lane = threadIdx.x & 63;
    int n0 = gstart[g], n1 = gstart[g + 1];

    float2 pn = make_float2(0.f, 0.f);
    float2 px = make_float2(0.f, 0.f);

    for (int n = n0 + s * 4 + wave; n < n1; n += 4 * SPLIT) {
        const ushort2* xr = (const ushort2*)(xb + (size_t)n * D_IN) + lane;
        ushort2 v = *xr;
        px.x += bf2f(v.x); px.y += bf2f(v.y);

        int d = deg[n];
        const int* cl = col + (size_t)n * MAXDEG;
        int cidx = (lane < d) ? cl[lane] : 0;   // one coalesced load, <=48 used

        float2 t = make_float2(0.f, 0.f);
        int j = 0;
        for (; j + 4 <= d; j += 4) {
            int s0 = __shfl(cidx, j);
            int s1 = __shfl(cidx, j + 1);
            int s2 = __shfl(cidx, j + 2);
            int s3 = __shfl(cidx, j + 3);
            ushort2 u0 = ((const ushort2*)(xb + (size_t)s0 * D_IN))[lane];
            ushort2 u1 = ((const ushort2*)(xb + (size_t)s1 * D_IN))[lane];
            ushort2 u2 = ((const ushort2*)(xb + (size_t)s2 * D_IN))[lane];
            ushort2 u3 = ((const ushort2*)(xb + (size_t)s3 * D_IN))[lane];
            t.x += bf2f(u0.x) + bf2f(u1.x) + bf2f(u2.x) + bf2f(u3.x);
            t.y += bf2f(u0.y) + bf2f(u1.y) + bf2f(u2.y) + bf2f(u3.y);
        }
        for (; j < d; ++j) {
            int sn = __shfl(cidx, j);
            ushort2 u = ((const ushort2*)(xb + (size_t)sn * D_IN))[lane];
            t.x += bf2f(u.x); t.y += bf2f(u.y);
        }
        if (d > 0) {
            float w = 1.f / (float)d;
            pn.x = fmaf(t.x, w, pn.x);
            pn.y = fmaf(t.y, w, pn.y);
        }
    }

    // 4 waves -> LDS, then one global atomic per feature per block
    atomicAdd(&sacc[2 * lane],             pn.x);
    atomicAdd(&sacc[2 * lane + 1],         pn.y);
    atomicAdd(&sacc[D_IN + 2 * lane],      px.x);
    atomicAdd(&sacc[D_IN + 2 * lane + 1],  px.y);
    __syncthreads();
    if (threadIdx.x < D_IN)
        atomicAdd(&Pn[g * D_IN + threadIdx.x], sacc[threadIdx.x]);
    else if (threadIdx.x < 2 * D_IN)
        atomicAdd(&Px[g * D_IN + threadIdx.x - D_IN], sacc[threadIdx.x]);
}

// ---------------------------------------------------------------------------
// Per-graph  h = (Pn@Wl + Px@Wr)/gcnt + bl  then the 64->32->16->8->1 MLP.
__global__ void final_kernel(
        const float* __restrict__ Pn, const float* __restrict__ Px,
        const float* __restrict__ Wl, const float* __restrict__ bl,
        const float* __restrict__ Wr,
        const float* __restrict__ W0, const float* __restrict__ b0,
        const float* __restrict__ W1, const float* __restrict__ b1,
        const float* __restrict__ W2, const float* __restrict__ b2,
        const float* __restrict__ W3, const float* __restrict__ b3,
        const int* __restrict__ gstart, float* __restrict__ out) {
    int g = blockIdx.x;
    int t = threadIdx.x;  // 64 threads
    __shared__ float h[H];
    __shared__ float a0[32];
    __shared__ float a1[16];
    __shared__ float a2[8];

    int ng = gstart[g + 1] - gstart[g];
    const float* pn = Pn + (size_t)g * D_IN;
    const float* px = Px + (size_t)g * D_IN;
    float acc = 0.f;
    for (int d = 0; d < D_IN; ++d)
        acc += pn[d] * Wl[d * H + t] + px[d] * Wr[d * H + t];
    h[t] = (ng > 0) ? (acc / (float)ng + bl[t]) : 0.f;  // empty graph -> 0
    __syncthreads();

    if (t < 32) { float a = b0[t]; for (int d = 0; d < H;  ++d) a += h[d]  * W0[d * 32 + t]; a0[t] = fmaxf(a, 0.f); }
    __syncthreads();
    if (t < 16) { float a = b1[t]; for (int d = 0; d < 32; ++d) a += a0[d] * W1[d * 16 + t]; a1[t] = fmaxf(a, 0.f); }
    __syncthreads();
    if (t < 8)  { float a = b2[t]; for (int d = 0; d < 16; ++d) a += a1[d] * W2[d * 8 + t];  a2[t] = fmaxf(a, 0.f); }
    __syncthreads();
    if (t == 0) { float a = b3[0]; for (int d = 0; d < 8;  ++d) a += a2[d] * W3[d]; out[g] = a; }
}

// ---------------------------------------------------------------------------
extern "C" void kernel_launch(void* const* d_in, const int* in_sizes, int n_in,
                              void* d_out, int out_size, void* d_ws, size_t ws_size,
                              hipStream_t stream) {
    const float* x     = (const float*)d_in[0];
    const int*   ei    = (const int*)  d_in[1];   // [2, N_EDGES]: row0=src, row1=dst
    const int*   batch = (const int*)  d_in[2];
    const float* Wl    = (const float*)d_in[3];
    const float* bl    = (const float*)d_in[4];
    const float* Wr    = (const float*)d_in[5];
    const float* W0    = (const float*)d_in[6];
    const float* b0    = (const float*)d_in[7];
    const float* W1    = (const float*)d_in[8];
    const float* b1    = (const float*)d_in[9];
    const float* W2    = (const float*)d_in[10];
    const float* b2    = (const float*)d_in[11];
    const float* W3    = (const float*)d_in[12];
    const float* b3    = (const float*)d_in[13];
    float* out = (float*)d_out;

    // workspace layout (aligned chunks)
    char* ws = (char*)d_ws;
    size_t off = 0;
    int*            deg    = (int*)(ws + off);            off += 204800;                        // 50000 ints
    int*            col    = (int*)(ws + off);            off += (size_t)N_NODES * MAXDEG * 4;  // 9.6 MB
    int*            gstart = (int*)(ws + off);            off += 4096;                          // 501 ints
    float*          Pn     = (float*)(ws + off);          off += N_GRAPHS * D_IN * 4;
    float*          Px     = (float*)(ws + off);          off += N_GRAPHS * D_IN * 4;
    unsigned short* xb     = (unsigned short*)(ws + off); off += (size_t)N_NODES * D_IN * 2;    // 12.8 MB

    hipMemsetAsync(deg, 0, N_NODES * sizeof(int), stream);
    hipMemsetAsync(Pn, 0, 2 * N_GRAPHS * D_IN * sizeof(float), stream);

    prep_kernel<<<CONV_BLOCKS + SCAT_BLOCKS + GST_BLOCKS, 256, 0, stream>>>(
        x, xb, ei, ei + N_EDGES, deg, col, batch, gstart);
    gather_kernel<<<N_GRAPHS * SPLIT, 256, 0, stream>>>(xb, col, deg, gstart, Pn, Px);
    final_kernel<<<N_GRAPHS, 64, 0, stream>>>(Pn, Px, Wl, bl, Wr,
                                              W0, b0, W1, b1, W2, b2, W3, b3,
                                              gstart, out);
}